// Round 1
// baseline (150.587 us; speedup 1.0000x reference)
//
#include <hip/hip_runtime.h>
#include <math.h>

#define LN_EPS 1e-5f

// One wave (64 lanes) per row. Lane l computes output cols l and l+64.
// Weights cached in registers, amortized over rows_per_wave rows.
__global__ __launch_bounds__(256) void h0_kernel(
    const float* __restrict__ stat, const float* __restrict__ fc_w,
    const float* __restrict__ fc_b, const float* __restrict__ ln_g,
    const float* __restrict__ ln_b, float* __restrict__ out,
    int n_rows, int rows_per_wave)
{
    const int lane = threadIdx.x & 63;
    const int wave = __builtin_amdgcn_readfirstlane(
        (int)((blockIdx.x * blockDim.x + threadIdx.x) >> 6));

    // Per-lane weight columns l and l+64 (32 regs)
    float w0[16], w1[16];
#pragma unroll
    for (int c = 0; c < 16; ++c) {
        w0[c] = fc_w[c * 128 + lane];
        w1[c] = fc_w[c * 128 + lane + 64];
    }
    const float b0 = fc_b[lane],      b1 = fc_b[lane + 64];
    const float g0 = ln_g[lane],      g1 = ln_g[lane + 64];
    const float e0 = ln_b[lane],      e1 = ln_b[lane + 64];

    int r = wave * rows_per_wave;
    int rend = r + rows_per_wave;
    if (rend > n_rows) rend = n_rows;

    for (; r < rend; ++r) {
        // wave-uniform row load (16 floats = 4x float4, 64B aligned)
        const float4* srow = reinterpret_cast<const float4*>(stat + (size_t)r * 16);
        float4 t0 = srow[0], t1 = srow[1], t2 = srow[2], t3 = srow[3];
        float s[16] = { t0.x, t0.y, t0.z, t0.w,  t1.x, t1.y, t1.z, t1.w,
                        t2.x, t2.y, t2.z, t2.w,  t3.x, t3.y, t3.z, t3.w };

        float x0 = b0, x1 = b1;
#pragma unroll
        for (int c = 0; c < 16; ++c) {
            x0 = fmaf(s[c], w0[c], x0);
            x1 = fmaf(s[c], w1[c], x1);
        }
        // exact GELU (erf form, matches torch F.gelu / jax approximate=False)
        x0 = 0.5f * x0 * (1.0f + erff(x0 * 0.70710678118654752f));
        x1 = 0.5f * x1 * (1.0f + erff(x1 * 0.70710678118654752f));

        // LayerNorm over 128 cols: wave-wide reduction of sum & sumsq
        float sum = x0 + x1;
        float sq  = x0 * x0 + x1 * x1;
#pragma unroll
        for (int o = 32; o > 0; o >>= 1) {
            sum += __shfl_xor(sum, o, 64);
            sq  += __shfl_xor(sq,  o, 64);
        }
        const float mu  = sum * (1.0f / 128.0f);
        const float var = sq * (1.0f / 128.0f) - mu * mu;
        const float inv = rsqrtf(var + LN_EPS);

        float* orow = out + (size_t)r * 128;
        orow[lane]      = (x0 - mu) * inv * g0 + e0;
        orow[lane + 64] = (x1 - mu) * inv * g1 + e1;
    }
}

// det[b*E + e] = -0.5 * || xy[b*N+src_e] - xy[b*N+dst_e] ||^2
// Thread handles 2 consecutive edges (int2 index load, float2 store). B=2.
__global__ __launch_bounds__(256) void det_kernel(
    const float* __restrict__ stat, const int* __restrict__ ei,
    float* __restrict__ det, int E, int N)
{
    int i = blockIdx.x * blockDim.x + threadIdx.x;   // pair index in [0, E)
    const int halfE = E >> 1;                        // pairs per batch
    if (i >= E) return;
    const int b = (i >= halfE) ? 1 : 0;
    const int j = i - b * halfE;                     // pair index within batch

    const int2* src2 = reinterpret_cast<const int2*>(ei);
    const int2* dst2 = reinterpret_cast<const int2*>(ei + E);
    int2 s = src2[j];
    int2 d = dst2[j];
    const int base = b * N;

    float2 ps0 = *reinterpret_cast<const float2*>(stat + (size_t)(base + s.x) * 16);
    float2 pd0 = *reinterpret_cast<const float2*>(stat + (size_t)(base + d.x) * 16);
    float2 ps1 = *reinterpret_cast<const float2*>(stat + (size_t)(base + s.y) * 16);
    float2 pd1 = *reinterpret_cast<const float2*>(stat + (size_t)(base + d.y) * 16);

    float dx0 = ps0.x - pd0.x, dy0 = ps0.y - pd0.y;
    float dx1 = ps1.x - pd1.x, dy1 = ps1.y - pd1.y;
    float2 v;
    v.x = -0.5f * (dx0 * dx0 + dy0 * dy0);
    v.y = -0.5f * (dx1 * dx1 + dy1 * dy1);
    reinterpret_cast<float2*>(det)[i] = v;
}

extern "C" void kernel_launch(void* const* d_in, const int* in_sizes, int n_in,
                              void* d_out, int out_size, void* d_ws, size_t ws_size,
                              hipStream_t stream) {
    const float* stat = (const float*)d_in[0];
    const int*   ei   = (const int*)d_in[1];
    const float* fc_w = (const float*)d_in[2];
    const float* fc_b = (const float*)d_in[3];
    const float* ln_g = (const float*)d_in[4];
    const float* ln_b = (const float*)d_in[5];
    float* out = (float*)d_out;

    const int n_rows = in_sizes[0] / 16;   // B*N = 100000
    const int E      = in_sizes[1] / 2;    // 1600000
    const int N      = n_rows / 2;         // B = 2

    float* H0  = out;
    float* det = out + (size_t)n_rows * 128;

    // H0: 1024 blocks * 4 waves = 4096 waves; ~25 rows/wave amortizes weight regs
    const int blocks_h = 1024;
    const int waves = blocks_h * 4;
    const int rpw = (n_rows + waves - 1) / waves;
    h0_kernel<<<blocks_h, 256, 0, stream>>>(stat, fc_w, fc_b, ln_g, ln_b, H0,
                                            n_rows, rpw);

    // det: E pairs (2 edges each), grid covers B*E outputs
    const int pairs = E;
    det_kernel<<<(pairs + 255) / 256, 256, 0, stream>>>(stat, ei, det, E, N);
}

// Round 2
// 131.989 us; speedup vs baseline: 1.1409x; 1.1409x over previous
//
#include <hip/hip_runtime.h>
#include <math.h>

#define LN_EPS 1e-5f

// One wave (64 lanes) per row. Lane l computes output cols l and l+64.
// Weights cached in registers; lane 0 also packs xy for both batches into ws:
//   xyp[n] = {x(b0,n), y(b0,n), x(b1,n), y(b1,n)}   (float4, N entries, 800 KB)
__global__ __launch_bounds__(256) void h0_kernel(
    const float* __restrict__ stat, const float* __restrict__ fc_w,
    const float* __restrict__ fc_b, const float* __restrict__ ln_g,
    const float* __restrict__ ln_b, float* __restrict__ out,
    float* __restrict__ xyp, int n_rows, int N, int rows_per_wave)
{
    const int lane = threadIdx.x & 63;
    const int wave = (int)((blockIdx.x * blockDim.x + threadIdx.x) >> 6);

    float w0[16], w1[16];
#pragma unroll
    for (int c = 0; c < 16; ++c) {
        w0[c] = fc_w[c * 128 + lane];
        w1[c] = fc_w[c * 128 + lane + 64];
    }
    const float b0 = fc_b[lane], b1 = fc_b[lane + 64];
    const float g0 = ln_g[lane], g1 = ln_g[lane + 64];
    const float e0 = ln_b[lane], e1 = ln_b[lane + 64];

    const int r0 = wave * rows_per_wave;
    int rend = r0 + rows_per_wave;
    if (rend > n_rows) rend = n_rows;

    for (int r = r0; r < rend; r += 2) {
        const bool two = (r + 1 < rend);
        // wave-uniform row loads (compiler scalarizes to s_load)
        const float4* srowA = reinterpret_cast<const float4*>(stat + (size_t)r * 16);
        float4 a0 = srowA[0], a1 = srowA[1], a2 = srowA[2], a3 = srowA[3];
        const float4* srowB = reinterpret_cast<const float4*>(stat + (size_t)(two ? r + 1 : r) * 16);
        float4 c0 = srowB[0], c1 = srowB[1], c2 = srowB[2], c3 = srowB[3];
        float sA[16] = { a0.x,a0.y,a0.z,a0.w, a1.x,a1.y,a1.z,a1.w,
                         a2.x,a2.y,a2.z,a2.w, a3.x,a3.y,a3.z,a3.w };
        float sB[16] = { c0.x,c0.y,c0.z,c0.w, c1.x,c1.y,c1.z,c1.w,
                         c2.x,c2.y,c2.z,c2.w, c3.x,c3.y,c3.z,c3.w };

        // pack xy into ws (both batches interleaved): row r -> xyp[n].{xy|zw}
        if (lane == 0) {
            int bA = (r >= N) ? 1 : 0;
            float* p = xyp + (size_t)(r - bA * N) * 4 + bA * 2;
            p[0] = sA[0]; p[1] = sA[1];
            if (two) {
                int rB = r + 1;
                int bB = (rB >= N) ? 1 : 0;
                float* q = xyp + (size_t)(rB - bB * N) * 4 + bB * 2;
                q[0] = sB[0]; q[1] = sB[1];
            }
        }

        float xA0 = b0, xA1 = b1, xB0 = b0, xB1 = b1;
#pragma unroll
        for (int c = 0; c < 16; ++c) {
            xA0 = fmaf(sA[c], w0[c], xA0);
            xA1 = fmaf(sA[c], w1[c], xA1);
            xB0 = fmaf(sB[c], w0[c], xB0);
            xB1 = fmaf(sB[c], w1[c], xB1);
        }
        const float k = 0.70710678118654752f;
        xA0 = 0.5f * xA0 * (1.0f + erff(xA0 * k));
        xA1 = 0.5f * xA1 * (1.0f + erff(xA1 * k));
        xB0 = 0.5f * xB0 * (1.0f + erff(xB0 * k));
        xB1 = 0.5f * xB1 * (1.0f + erff(xB1 * k));

        // two independent wave reductions, interleaved for chain ILP
        float sumA = xA0 + xA1, sqA = xA0 * xA0 + xA1 * xA1;
        float sumB = xB0 + xB1, sqB = xB0 * xB0 + xB1 * xB1;
#pragma unroll
        for (int o = 32; o > 0; o >>= 1) {
            sumA += __shfl_xor(sumA, o, 64);
            sumB += __shfl_xor(sumB, o, 64);
            sqA  += __shfl_xor(sqA,  o, 64);
            sqB  += __shfl_xor(sqB,  o, 64);
        }
        const float muA = sumA * (1.0f / 128.0f);
        const float invA = rsqrtf(sqA * (1.0f / 128.0f) - muA * muA + LN_EPS);
        const float muB = sumB * (1.0f / 128.0f);
        const float invB = rsqrtf(sqB * (1.0f / 128.0f) - muB * muB + LN_EPS);

        float* orowA = out + (size_t)r * 128;
        orowA[lane]      = (xA0 - muA) * invA * g0 + e0;
        orowA[lane + 64] = (xA1 - muA) * invA * g1 + e1;
        if (two) {
            float* orowB = out + (size_t)(r + 1) * 128;
            orowB[lane]      = (xB0 - muB) * invB * g0 + e0;
            orowB[lane + 64] = (xB1 - muB) * invB * g1 + e1;
        }
    }
}

// Packed-table det: thread handles 2 edges x 2 batches.
// det[b*E+e] = -0.5*||xy[b,src]-xy[b,dst]||^2 ; one float4 gather serves both b.
__global__ __launch_bounds__(256) void det_kernel_packed(
    const float4* __restrict__ xyp, const int* __restrict__ ei,
    float* __restrict__ det, int E)
{
    int i = (blockIdx.x * blockDim.x + threadIdx.x) * 2;
    if (i >= E) return;
    int2 s = *reinterpret_cast<const int2*>(ei + i);
    int2 d = *reinterpret_cast<const int2*>(ei + E + i);
    float4 as = xyp[s.x], ad = xyp[d.x];
    float4 bs = xyp[s.y], bd = xyp[d.y];

    float ax0 = as.x - ad.x, ay0 = as.y - ad.y;   // edge i,   batch 0
    float ax1 = as.z - ad.z, ay1 = as.w - ad.w;   // edge i,   batch 1
    float bx0 = bs.x - bd.x, by0 = bs.y - bd.y;   // edge i+1, batch 0
    float bx1 = bs.z - bd.z, by1 = bs.w - bd.w;   // edge i+1, batch 1

    float2 v0, v1;
    v0.x = -0.5f * (ax0 * ax0 + ay0 * ay0);
    v0.y = -0.5f * (bx0 * bx0 + by0 * by0);
    v1.x = -0.5f * (ax1 * ax1 + ay1 * ay1);
    v1.y = -0.5f * (bx1 * bx1 + by1 * by1);
    *reinterpret_cast<float2*>(det + i)     = v0;
    *reinterpret_cast<float2*>(det + E + i) = v1;
}

// Fallback (ws too small): gather directly from static rows (stride 16 floats).
__global__ __launch_bounds__(256) void det_kernel_direct(
    const float* __restrict__ stat, const int* __restrict__ ei,
    float* __restrict__ det, int E, int N)
{
    int i = (blockIdx.x * blockDim.x + threadIdx.x) * 2;
    if (i >= E) return;
    int2 s = *reinterpret_cast<const int2*>(ei + i);
    int2 d = *reinterpret_cast<const int2*>(ei + E + i);
#pragma unroll
    for (int b = 0; b < 2; ++b) {
        const float* base = stat + (size_t)b * N * 16;
        float2 ps0 = *reinterpret_cast<const float2*>(base + (size_t)s.x * 16);
        float2 pd0 = *reinterpret_cast<const float2*>(base + (size_t)d.x * 16);
        float2 ps1 = *reinterpret_cast<const float2*>(base + (size_t)s.y * 16);
        float2 pd1 = *reinterpret_cast<const float2*>(base + (size_t)d.y * 16);
        float dx0 = ps0.x - pd0.x, dy0 = ps0.y - pd0.y;
        float dx1 = ps1.x - pd1.x, dy1 = ps1.y - pd1.y;
        float2 v;
        v.x = -0.5f * (dx0 * dx0 + dy0 * dy0);
        v.y = -0.5f * (dx1 * dx1 + dy1 * dy1);
        *reinterpret_cast<float2*>(det + (size_t)b * E + i) = v;
    }
}

extern "C" void kernel_launch(void* const* d_in, const int* in_sizes, int n_in,
                              void* d_out, int out_size, void* d_ws, size_t ws_size,
                              hipStream_t stream) {
    const float* stat = (const float*)d_in[0];
    const int*   ei   = (const int*)d_in[1];
    const float* fc_w = (const float*)d_in[2];
    const float* fc_b = (const float*)d_in[3];
    const float* ln_g = (const float*)d_in[4];
    const float* ln_b = (const float*)d_in[5];
    float* out = (float*)d_out;

    const int n_rows = in_sizes[0] / 16;   // B*N = 100000
    const int E      = in_sizes[1] / 2;    // 1600000
    const int N      = n_rows / 2;         // B = 2

    float* H0  = out;
    float* det = out + (size_t)n_rows * 128;
    float* xyp = (float*)d_ws;
    const bool use_ws = (ws_size >= (size_t)N * 4 * sizeof(float));

    // h0: 8 rows/wave -> 12500 waves, 3125 blocks (more TLP than 25 rows/wave)
    const int rpw = 8;
    const int waves = (n_rows + rpw - 1) / rpw;
    const int blocks_h = (waves + 3) / 4;
    h0_kernel<<<blocks_h, 256, 0, stream>>>(stat, fc_w, fc_b, ln_g, ln_b, H0,
                                            use_ws ? xyp : H0 /*unused*/,
                                            n_rows, use_ws ? N : 0x7fffffff, rpw);

    const int pairs = (E + 1) / 2;
    const int blocks_d = (pairs + 255) / 256;
    if (use_ws) {
        det_kernel_packed<<<blocks_d, 256, 0, stream>>>(
            (const float4*)xyp, ei, det, E);
    } else {
        det_kernel_direct<<<blocks_d, 256, 0, stream>>>(stat, ei, det, E, N);
    }
}

// Round 3
// 119.333 us; speedup vs baseline: 1.2619x; 1.1061x over previous
//
#include <hip/hip_runtime.h>
#include <math.h>

#define LN_EPS 1e-5f

// ---------- DPP wave64 sum: 6 fused v_add_f32_dpp + 1 readlane ----------
template<int CTRL>
__device__ __forceinline__ float dppadd(float x) {
    int y = __builtin_amdgcn_update_dpp(0, __float_as_int(x), CTRL, 0xf, 0xf, true);
    return x + __int_as_float(y);
}
__device__ __forceinline__ float wave_sum(float x) {
    x = dppadd<0xB1>(x);    // quad_perm [1,0,3,2]  (xor 1)
    x = dppadd<0x4E>(x);    // quad_perm [2,3,0,1]  (xor 2)
    x = dppadd<0x141>(x);   // row_half_mirror      (xor 4)
    x = dppadd<0x140>(x);   // row_mirror           (xor 8)
    x = dppadd<0x142>(x);   // row_bcast:15         (16 -> 32)
    x = dppadd<0x143>(x);   // row_bcast:31         (32 -> 64), total in lane 63
    return __int_as_float(__builtin_amdgcn_readlane(__float_as_int(x), 63));
}

// tanh-form GELU: x * sigmoid(1.59577*(x + 0.044715 x^3)); max abs err ~3e-3
__device__ __forceinline__ float gelu_f(float x) {
    float t = x * fmaf(x * x, 0.044715f, 1.0f) * 1.5957691216057308f;
    float e = __expf(-t);
    return x * __builtin_amdgcn_rcpf(1.0f + e);
}

// One wave per 2 rows' iteration. Lane l computes cols l and l+64.
__global__ __launch_bounds__(256) void h0_kernel(
    const float* __restrict__ stat, const float* __restrict__ fc_w,
    const float* __restrict__ fc_b, const float* __restrict__ ln_g,
    const float* __restrict__ ln_b, float* __restrict__ out,
    int n_rows, int rows_per_wave)
{
    const int lane = threadIdx.x & 63;
    const int wave = (int)((blockIdx.x * blockDim.x + threadIdx.x) >> 6);

    float w0[16], w1[16];
#pragma unroll
    for (int c = 0; c < 16; ++c) {
        w0[c] = fc_w[c * 128 + lane];
        w1[c] = fc_w[c * 128 + lane + 64];
    }
    const float b0 = fc_b[lane], b1 = fc_b[lane + 64];
    const float g0 = ln_g[lane], g1 = ln_g[lane + 64];
    const float e0 = ln_b[lane], e1 = ln_b[lane + 64];

    const int r0 = wave * rows_per_wave;
    int rend = r0 + rows_per_wave;
    if (rend > n_rows) rend = n_rows;

    for (int r = r0; r < rend; r += 2) {
        const bool two = (r + 1 < rend);
        // row data is wave-uniform; readfirstlane lets compiler scalarize
        const int ra = __builtin_amdgcn_readfirstlane(r);
        const int rb = __builtin_amdgcn_readfirstlane(two ? r + 1 : r);
        const float4* srowA = reinterpret_cast<const float4*>(stat + (size_t)ra * 16);
        const float4* srowB = reinterpret_cast<const float4*>(stat + (size_t)rb * 16);
        float4 a0 = srowA[0], a1 = srowA[1], a2 = srowA[2], a3 = srowA[3];
        float4 c0 = srowB[0], c1 = srowB[1], c2 = srowB[2], c3 = srowB[3];
        float sA[16] = { a0.x,a0.y,a0.z,a0.w, a1.x,a1.y,a1.z,a1.w,
                         a2.x,a2.y,a2.z,a2.w, a3.x,a3.y,a3.z,a3.w };
        float sB[16] = { c0.x,c0.y,c0.z,c0.w, c1.x,c1.y,c1.z,c1.w,
                         c2.x,c2.y,c2.z,c2.w, c3.x,c3.y,c3.z,c3.w };

        float xA0 = b0, xA1 = b1, xB0 = b0, xB1 = b1;
#pragma unroll
        for (int c = 0; c < 16; ++c) {
            xA0 = fmaf(sA[c], w0[c], xA0);
            xA1 = fmaf(sA[c], w1[c], xA1);
            xB0 = fmaf(sB[c], w0[c], xB0);
            xB1 = fmaf(sB[c], w1[c], xB1);
        }
        xA0 = gelu_f(xA0); xA1 = gelu_f(xA1);
        xB0 = gelu_f(xB0); xB1 = gelu_f(xB1);

        const float sumA = wave_sum(xA0 + xA1);
        const float sqA  = wave_sum(xA0 * xA0 + xA1 * xA1);
        const float sumB = wave_sum(xB0 + xB1);
        const float sqB  = wave_sum(xB0 * xB0 + xB1 * xB1);

        const float muA = sumA * (1.0f / 128.0f);
        const float invA = rsqrtf(sqA * (1.0f / 128.0f) - muA * muA + LN_EPS);
        const float muB = sumB * (1.0f / 128.0f);
        const float invB = rsqrtf(sqB * (1.0f / 128.0f) - muB * muB + LN_EPS);

        float* orowA = out + (size_t)r * 128;
        orowA[lane]      = (xA0 - muA) * invA * g0 + e0;
        orowA[lane + 64] = (xA1 - muA) * invA * g1 + e1;
        if (two) {
            float* orowB = out + (size_t)(r + 1) * 128;
            orowB[lane]      = (xB0 - muB) * invB * g0 + e0;
            orowB[lane + 64] = (xB1 - muB) * invB * g1 + e1;
        }
    }
}

// Pack xy of both batches: xyp[n] = {x(b0,n), y(b0,n), x(b1,n), y(b1,n)}
__global__ __launch_bounds__(256) void pack_kernel(
    const float* __restrict__ stat, float4* __restrict__ xyp, int N)
{
    int n = blockIdx.x * blockDim.x + threadIdx.x;
    if (n >= N) return;
    float2 a = *reinterpret_cast<const float2*>(stat + (size_t)n * 16);
    float2 b = *reinterpret_cast<const float2*>(stat + (size_t)(n + N) * 16);
    xyp[n] = make_float4(a.x, a.y, b.x, b.y);
}

// 4 edges x 2 batches per thread: 2 int4 index loads, 8 float4 gathers
// in flight, 2 float4 stores. One gather serves both batches.
__global__ __launch_bounds__(256) void det_kernel4(
    const float4* __restrict__ xyp, const int* __restrict__ ei,
    float* __restrict__ det, int E)
{
    int i = (blockIdx.x * blockDim.x + threadIdx.x) * 4;
    if (i >= E) return;
    int4 s = *reinterpret_cast<const int4*>(ei + i);
    int4 d = *reinterpret_cast<const int4*>(ei + E + i);
    float4 s0 = xyp[s.x], d0 = xyp[d.x];
    float4 s1 = xyp[s.y], d1 = xyp[d.y];
    float4 s2 = xyp[s.z], d2 = xyp[d.z];
    float4 s3 = xyp[s.w], d3 = xyp[d.w];

    float4 o0, o1;
    {
        float dx = s0.x - d0.x, dy = s0.y - d0.y; o0.x = -0.5f * (dx*dx + dy*dy);
        dx = s0.z - d0.z; dy = s0.w - d0.w;       o1.x = -0.5f * (dx*dx + dy*dy);
        dx = s1.x - d1.x; dy = s1.y - d1.y;       o0.y = -0.5f * (dx*dx + dy*dy);
        dx = s1.z - d1.z; dy = s1.w - d1.w;       o1.y = -0.5f * (dx*dx + dy*dy);
        dx = s2.x - d2.x; dy = s2.y - d2.y;       o0.z = -0.5f * (dx*dx + dy*dy);
        dx = s2.z - d2.z; dy = s2.w - d2.w;       o1.z = -0.5f * (dx*dx + dy*dy);
        dx = s3.x - d3.x; dy = s3.y - d3.y;       o0.w = -0.5f * (dx*dx + dy*dy);
        dx = s3.z - d3.z; dy = s3.w - d3.w;       o1.w = -0.5f * (dx*dx + dy*dy);
    }
    *reinterpret_cast<float4*>(det + i)     = o0;
    *reinterpret_cast<float4*>(det + E + i) = o1;
}

// Fallback (ws too small): gather directly from static rows.
__global__ __launch_bounds__(256) void det_kernel_direct(
    const float* __restrict__ stat, const int* __restrict__ ei,
    float* __restrict__ det, int E, int N)
{
    int i = (blockIdx.x * blockDim.x + threadIdx.x) * 2;
    if (i >= E) return;
    int2 s = *reinterpret_cast<const int2*>(ei + i);
    int2 d = *reinterpret_cast<const int2*>(ei + E + i);
#pragma unroll
    for (int b = 0; b < 2; ++b) {
        const float* base = stat + (size_t)b * N * 16;
        float2 ps0 = *reinterpret_cast<const float2*>(base + (size_t)s.x * 16);
        float2 pd0 = *reinterpret_cast<const float2*>(base + (size_t)d.x * 16);
        float2 ps1 = *reinterpret_cast<const float2*>(base + (size_t)s.y * 16);
        float2 pd1 = *reinterpret_cast<const float2*>(base + (size_t)d.y * 16);
        float dx0 = ps0.x - pd0.x, dy0 = ps0.y - pd0.y;
        float dx1 = ps1.x - pd1.x, dy1 = ps1.y - pd1.y;
        float2 v;
        v.x = -0.5f * (dx0 * dx0 + dy0 * dy0);
        v.y = -0.5f * (dx1 * dx1 + dy1 * dy1);
        *reinterpret_cast<float2*>(det + (size_t)b * E + i) = v;
    }
}

extern "C" void kernel_launch(void* const* d_in, const int* in_sizes, int n_in,
                              void* d_out, int out_size, void* d_ws, size_t ws_size,
                              hipStream_t stream) {
    const float* stat = (const float*)d_in[0];
    const int*   ei   = (const int*)d_in[1];
    const float* fc_w = (const float*)d_in[2];
    const float* fc_b = (const float*)d_in[3];
    const float* ln_g = (const float*)d_in[4];
    const float* ln_b = (const float*)d_in[5];
    float* out = (float*)d_out;

    const int n_rows = in_sizes[0] / 16;   // B*N = 100000
    const int E      = in_sizes[1] / 2;    // 1600000
    const int N      = n_rows / 2;         // B = 2

    float* H0  = out;
    float* det = out + (size_t)n_rows * 128;
    float* xyp = (float*)d_ws;
    const bool use_ws = (ws_size >= (size_t)N * 4 * sizeof(float)) && (E % 4 == 0);

    if (use_ws) {
        pack_kernel<<<(N + 255) / 256, 256, 0, stream>>>(stat, (float4*)xyp, N);
        const int quads = E / 4;
        det_kernel4<<<(quads + 255) / 256, 256, 0, stream>>>(
            (const float4*)xyp, ei, det, E);
    } else {
        const int pairs = (E + 1) / 2;
        det_kernel_direct<<<(pairs + 255) / 256, 256, 0, stream>>>(stat, ei, det, E, N);
    }

    const int rpw = 8;
    const int waves = (n_rows + rpw - 1) / rpw;
    const int blocks_h = (waves + 3) / 4;
    h0_kernel<<<blocks_h, 256, 0, stream>>>(stat, fc_w, fc_b, ln_g, ln_b, H0,
                                            n_rows, rpw);
}

// Round 5
// 117.208 us; speedup vs baseline: 1.2848x; 1.0181x over previous
//
#include <hip/hip_runtime.h>
#include <math.h>

#define LN_EPS 1e-5f

// native clang vector types — required by __builtin_nontemporal_*
typedef int   vint4  __attribute__((ext_vector_type(4)));
typedef float vfloat4 __attribute__((ext_vector_type(4)));

// ---------- DPP wave64 sum: 6 fused v_add_f32_dpp + 1 readlane ----------
template<int CTRL>
__device__ __forceinline__ float dppadd(float x) {
    int y = __builtin_amdgcn_update_dpp(0, __float_as_int(x), CTRL, 0xf, 0xf, true);
    return x + __int_as_float(y);
}
__device__ __forceinline__ float wave_sum(float x) {
    x = dppadd<0xB1>(x);    // quad_perm xor1
    x = dppadd<0x4E>(x);    // quad_perm xor2
    x = dppadd<0x141>(x);   // row_half_mirror xor4
    x = dppadd<0x140>(x);   // row_mirror xor8
    x = dppadd<0x142>(x);   // row_bcast:15
    x = dppadd<0x143>(x);   // row_bcast:31 -> total in lane 63
    return __int_as_float(__builtin_amdgcn_readlane(__float_as_int(x), 63));
}

// tanh-form GELU via v_exp/v_rcp; max abs err ~3e-3 (threshold 0.63)
__device__ __forceinline__ float gelu_f(float x) {
    float t = x * fmaf(x * x, 0.044715f, 1.0f) * 1.5957691216057308f;
    float e = __expf(-t);
    return x * __builtin_amdgcn_rcpf(1.0f + e);
}

// Pack xy of both batches: xyp[n] = {x(b0,n), y(b0,n), x(b1,n), y(b1,n)}
__global__ __launch_bounds__(256) void pack_kernel(
    const float* __restrict__ stat, float4* __restrict__ xyp, int N)
{
    int n = blockIdx.x * blockDim.x + threadIdx.x;
    if (n >= N) return;
    float2 a = *reinterpret_cast<const float2*>(stat + (size_t)n * 16);
    float2 b = *reinterpret_cast<const float2*>(stat + (size_t)(n + N) * 16);
    xyp[n] = make_float4(a.x, a.y, b.x, b.y);
}

// Fused grid-partitioned kernel: every 3rd block does det (latency/TA-bound),
// the other two-thirds do h0 (VALU/write-BW-bound). Co-residency lets the
// two phases hide each other's stalls. Streaming traffic is non-temporal so
// the 800 KB xyp gather table stays L2-resident.
__global__ __launch_bounds__(256) void fused_kernel(
    const float* __restrict__ stat, const float* __restrict__ fc_w,
    const float* __restrict__ fc_b, const float* __restrict__ ln_g,
    const float* __restrict__ ln_b, float* __restrict__ out,
    const float4* __restrict__ xyp, const int* __restrict__ ei,
    float* __restrict__ det,
    int n_rows, int rows_per_wave, int E, int nDetBlocks, int nH0Blocks)
{
    const int bid = blockIdx.x;
    const int q = bid / 3, k = bid % 3;

    if (k == 0) {
        // ---------------- det: 4 edges x 2 batches per thread ----------------
        const int det_id = q;
        if (det_id >= nDetBlocks) return;
        int i = (det_id * 256 + (int)threadIdx.x) * 4;
        if (i >= E) return;
        vint4 s = __builtin_nontemporal_load(reinterpret_cast<const vint4*>(ei + i));
        vint4 d = __builtin_nontemporal_load(reinterpret_cast<const vint4*>(ei + E + i));
        float4 s0 = xyp[s.x], d0 = xyp[d.x];
        float4 s1 = xyp[s.y], d1 = xyp[d.y];
        float4 s2 = xyp[s.z], d2 = xyp[d.z];
        float4 s3 = xyp[s.w], d3 = xyp[d.w];

        vfloat4 o0, o1;
        float dx, dy;
        dx = s0.x - d0.x; dy = s0.y - d0.y; o0.x = -0.5f * (dx*dx + dy*dy);
        dx = s0.z - d0.z; dy = s0.w - d0.w; o1.x = -0.5f * (dx*dx + dy*dy);
        dx = s1.x - d1.x; dy = s1.y - d1.y; o0.y = -0.5f * (dx*dx + dy*dy);
        dx = s1.z - d1.z; dy = s1.w - d1.w; o1.y = -0.5f * (dx*dx + dy*dy);
        dx = s2.x - d2.x; dy = s2.y - d2.y; o0.z = -0.5f * (dx*dx + dy*dy);
        dx = s2.z - d2.z; dy = s2.w - d2.w; o1.z = -0.5f * (dx*dx + dy*dy);
        dx = s3.x - d3.x; dy = s3.y - d3.y; o0.w = -0.5f * (dx*dx + dy*dy);
        dx = s3.z - d3.z; dy = s3.w - d3.w; o1.w = -0.5f * (dx*dx + dy*dy);
        __builtin_nontemporal_store(o0, reinterpret_cast<vfloat4*>(det + i));
        __builtin_nontemporal_store(o1, reinterpret_cast<vfloat4*>(det + E + i));
        return;
    }

    // ---------------- h0: one wave per row-pair iteration ----------------
    const int h0_id = q * 2 + (k - 1);
    if (h0_id >= nH0Blocks) return;

    const int lane = threadIdx.x & 63;
    const int wave = h0_id * 4 + ((int)threadIdx.x >> 6);

    float w0[16], w1[16];
#pragma unroll
    for (int c = 0; c < 16; ++c) {
        w0[c] = fc_w[c * 128 + lane];
        w1[c] = fc_w[c * 128 + lane + 64];
    }
    const float b0 = fc_b[lane], b1 = fc_b[lane + 64];
    const float g0 = ln_g[lane], g1 = ln_g[lane + 64];
    const float e0 = ln_b[lane], e1 = ln_b[lane + 64];

    const int r0 = wave * rows_per_wave;
    int rend = r0 + rows_per_wave;
    if (rend > n_rows) rend = n_rows;

    for (int r = r0; r < rend; r += 2) {
        const bool two = (r + 1 < rend);
        const int ra = __builtin_amdgcn_readfirstlane(r);
        const int rb = __builtin_amdgcn_readfirstlane(two ? r + 1 : r);
        const float4* srowA = reinterpret_cast<const float4*>(stat + (size_t)ra * 16);
        const float4* srowB = reinterpret_cast<const float4*>(stat + (size_t)rb * 16);
        float4 a0 = srowA[0], a1 = srowA[1], a2 = srowA[2], a3 = srowA[3];
        float4 c0 = srowB[0], c1 = srowB[1], c2 = srowB[2], c3 = srowB[3];
        float sA[16] = { a0.x,a0.y,a0.z,a0.w, a1.x,a1.y,a1.z,a1.w,
                         a2.x,a2.y,a2.z,a2.w, a3.x,a3.y,a3.z,a3.w };
        float sB[16] = { c0.x,c0.y,c0.z,c0.w, c1.x,c1.y,c1.z,c1.w,
                         c2.x,c2.y,c2.z,c2.w, c3.x,c3.y,c3.z,c3.w };

        float xA0 = b0, xA1 = b1, xB0 = b0, xB1 = b1;
#pragma unroll
        for (int c = 0; c < 16; ++c) {
            xA0 = fmaf(sA[c], w0[c], xA0);
            xA1 = fmaf(sA[c], w1[c], xA1);
            xB0 = fmaf(sB[c], w0[c], xB0);
            xB1 = fmaf(sB[c], w1[c], xB1);
        }
        xA0 = gelu_f(xA0); xA1 = gelu_f(xA1);
        xB0 = gelu_f(xB0); xB1 = gelu_f(xB1);

        const float sumA = wave_sum(xA0 + xA1);
        const float sqA  = wave_sum(xA0 * xA0 + xA1 * xA1);
        const float sumB = wave_sum(xB0 + xB1);
        const float sqB  = wave_sum(xB0 * xB0 + xB1 * xB1);

        const float muA = sumA * (1.0f / 128.0f);
        const float invA = rsqrtf(sqA * (1.0f / 128.0f) - muA * muA + LN_EPS);
        const float muB = sumB * (1.0f / 128.0f);
        const float invB = rsqrtf(sqB * (1.0f / 128.0f) - muB * muB + LN_EPS);

        float* orowA = out + (size_t)r * 128;
        __builtin_nontemporal_store((xA0 - muA) * invA * g0 + e0, orowA + lane);
        __builtin_nontemporal_store((xA1 - muA) * invA * g1 + e1, orowA + lane + 64);
        if (two) {
            float* orowB = out + (size_t)(r + 1) * 128;
            __builtin_nontemporal_store((xB0 - muB) * invB * g0 + e0, orowB + lane);
            __builtin_nontemporal_store((xB1 - muB) * invB * g1 + e1, orowB + lane + 64);
        }
    }
}

// Fallback (ws too small / E%4 != 0): gather directly from static rows.
__global__ __launch_bounds__(256) void det_kernel_direct(
    const float* __restrict__ stat, const int* __restrict__ ei,
    float* __restrict__ det, int E, int N)
{
    int i = (blockIdx.x * blockDim.x + threadIdx.x) * 2;
    if (i >= E) return;
    int2 s = *reinterpret_cast<const int2*>(ei + i);
    int2 d = *reinterpret_cast<const int2*>(ei + E + i);
#pragma unroll
    for (int b = 0; b < 2; ++b) {
        const float* base = stat + (size_t)b * N * 16;
        float2 ps0 = *reinterpret_cast<const float2*>(base + (size_t)s.x * 16);
        float2 pd0 = *reinterpret_cast<const float2*>(base + (size_t)d.x * 16);
        float2 ps1 = *reinterpret_cast<const float2*>(base + (size_t)s.y * 16);
        float2 pd1 = *reinterpret_cast<const float2*>(base + (size_t)d.y * 16);
        float dx0 = ps0.x - pd0.x, dy0 = ps0.y - pd0.y;
        float dx1 = ps1.x - pd1.x, dy1 = ps1.y - pd1.y;
        float2 v;
        v.x = -0.5f * (dx0 * dx0 + dy0 * dy0);
        v.y = -0.5f * (dx1 * dx1 + dy1 * dy1);
        *reinterpret_cast<float2*>(det + (size_t)b * E + i) = v;
    }
}

extern "C" void kernel_launch(void* const* d_in, const int* in_sizes, int n_in,
                              void* d_out, int out_size, void* d_ws, size_t ws_size,
                              hipStream_t stream) {
    const float* stat = (const float*)d_in[0];
    const int*   ei   = (const int*)d_in[1];
    const float* fc_w = (const float*)d_in[2];
    const float* fc_b = (const float*)d_in[3];
    const float* ln_g = (const float*)d_in[4];
    const float* ln_b = (const float*)d_in[5];
    float* out = (float*)d_out;

    const int n_rows = in_sizes[0] / 16;   // B*N = 100000
    const int E      = in_sizes[1] / 2;    // 1600000
    const int N      = n_rows / 2;         // B = 2

    float* H0  = out;
    float* det = out + (size_t)n_rows * 128;
    float* xyp = (float*)d_ws;
    const bool use_ws = (ws_size >= (size_t)N * 4 * sizeof(float)) && (E % 4 == 0);

    const int rpw = 8;
    const int waves = (n_rows + rpw - 1) / rpw;
    const int nH0Blocks = (waves + 3) / 4;                 // 3125

    if (use_ws) {
        pack_kernel<<<(N + 255) / 256, 256, 0, stream>>>(stat, (float4*)xyp, N);
        const int quads = E / 4;
        const int nDetBlocks = (quads + 255) / 256;        // 1563
        int need = nDetBlocks;
        int needH = (nH0Blocks + 1) / 2;
        int G = 3 * (need > needH ? need : needH) + 3;     // extra blocks exit early
        fused_kernel<<<G, 256, 0, stream>>>(stat, fc_w, fc_b, ln_g, ln_b, H0,
                                            (const float4*)xyp, ei, det,
                                            n_rows, rpw, E, nDetBlocks, nH0Blocks);
    } else {
        const int pairs = (E + 1) / 2;
        det_kernel_direct<<<(pairs + 255) / 256, 256, 0, stream>>>(stat, ei, det, E, N);
        // reuse fused kernel in h0-only mode: nDetBlocks=0
        int G = 3 * ((nH0Blocks + 1) / 2) + 3;
        fused_kernel<<<G, 256, 0, stream>>>(stat, fc_w, fc_b, ln_g, ln_b, H0,
                                            (const float4*)xyp, ei, det,
                                            n_rows, rpw, 0, 0, nH0Blocks);
    }
}